// Round 12
// baseline (362.535 us; speedup 1.0000x reference)
//
#include <hip/hip_runtime.h>
#include <hip/hip_bf16.h>

#define BB 32
#define SS 2048
#define DD 1024
#define UU 1024
#define MBLK 64
#define AST 40  // A LDS row stride in shorts (80 B)

typedef short bf16x8 __attribute__((ext_vector_type(8)));
typedef float f32x4 __attribute__((ext_vector_type(4)));
typedef unsigned int u32;

__device__ __forceinline__ unsigned short f2bf(float x) {
    union { float f; unsigned int u; } v; v.f = x;
    unsigned int r = v.u + 0x7fffu + ((v.u >> 16) & 1u);
    return (unsigned short)(r >> 16);
}

__device__ __forceinline__ f32x4 ntload4(const float* p) {
    return __builtin_nontemporal_load(reinterpret_cast<const f32x4*>(p));
}

__device__ __forceinline__ u32 cvtpk(float lo, float hi) {
    u32 r;
    asm("v_cvt_pk_bf16_f32 %0, %1, %2" : "=v"(r) : "v"(lo), "v"(hi));
    return r;
}

// ---------------- K0: zero the score accumulator ----------------
__global__ void zero_kernel(float* __restrict__ score) {
    score[blockIdx.x * 256 + threadIdx.x] = 0.f;
}

// ---------------- K1a: q_proj = query@w1 + b1 + b2 ----------------
__global__ void qproj_kernel(const float* __restrict__ query, const float* __restrict__ w1,
                             const float* __restrict__ b1, const float* __restrict__ b2,
                             float* __restrict__ qp2) {
    __shared__ float qs[DD];
    const int b = blockIdx.x;   // 32
    const int uc = blockIdx.y;  // 4
    const int t = threadIdx.x;  // 256
    for (int i = t; i < DD; i += 256) qs[i] = query[b * DD + i];
    __syncthreads();
    const int u = uc * 256 + t;
    float acc = 0.f;
#pragma unroll 4
    for (int d = 0; d < DD; ++d) acc = fmaf(qs[d], w1[d * UU + u], acc);
    qp2[b * UU + u] = acc + b1[u] + b2[u];
}

// ---------------- K1b: fragment-packed B for 16x16x32: w2q[uq][ks][lane][8] ----
// lane l: col = uq*16 + (l&15), k = ks*32 + (l>>4)*8 + e  (R2-verified frag layout)
__global__ void w2q_kernel(const float* __restrict__ w2, unsigned short* __restrict__ w2q) {
    const int tid = blockIdx.x * 256 + threadIdx.x;  // 0..131071
    const int lane = tid & 63;
    const int pair = tid >> 6;     // uq*32 + ks
    const int ks = pair & 31;
    const int uq = pair >> 5;      // 0..63
    const int colg = uq * 16 + (lane & 15);
    const int k0 = ks * 32 + (lane >> 4) * 8;
    bf16x8 pk;
#pragma unroll
    for (int e = 0; e < 8; ++e) pk[e] = (short)f2bf(w2[(size_t)(k0 + e) * UU + colg]);
    *reinterpret_cast<bf16x8*>(&w2q[(size_t)tid * 8]) = pk;
}

// ---------------- K2: fused GEMM + tanh + wv-reduce -> atomic score partials ----
// Split-U: 2048 blocks = (b, stile, uhalf); each block 64 rows x 512 U-cols.
// 512 thr / 8 waves; wave = 64x64 via 16x16x32 (acc[4][4] f32x4 = 64 VGPR).
// launch_bounds(512,4) -> <=128 regs -> TWO independent blocks/CU (barrier drains
// of one block overlap the other's MFMAs). BK=32, A reg-ring depth 2, raw barriers.
// bv dropped: softmax is shift-invariant. Partials atomicAdd'ed into pre-zeroed score.
__global__ __launch_bounds__(512, 4)
void score_kernel(const float* __restrict__ values, const unsigned short* __restrict__ w2q,
                  const float* __restrict__ qp2, const float* __restrict__ wv,
                  float* __restrict__ score) {
    __shared__ __align__(16) unsigned short As[2][MBLK * AST];  // 2 x 5 KB
    __shared__ float ssum[8][MBLK];                              // 2 KB

    const int blk = blockIdx.x;        // 2048
    const int b = blk >> 6;            // 32
    const int stile = (blk >> 1) & 31; // 32
    const int uh = blk & 1;            // uhalf fastest: A-tile reread stays cache-hot
    const int s0 = stile * MBLK;
    const int tid = threadIdx.x;
    const int lane = tid & 63;
    const int wid = tid >> 6;          // 0..7
    const int arow = lane & 15;
    const int kgrp = (lane >> 4) * 8;

    // wave's 64 U-cols start at uq0*16
    const int uq0 = uh * 32 + wid * 4;

    // staging: 8 thr/row, f32x4 each (64 rows x 32 k per step)
    const int srow = tid >> 3;         // 0..63
    const int sc = tid & 7;            // 0..7
    const float* pA = values + ((size_t)b * SS + s0 + srow) * DD + sc * 4;
    const int wslot = srow * (AST / 2) + sc * 2;  // u32 slot

    const unsigned short* wq = w2q + (size_t)lane * 8;

    f32x4 acc[4][4];
#pragma unroll
    for (int mf = 0; mf < 4; ++mf)
#pragma unroll
        for (int nf = 0; nf < 4; ++nf) { f32x4 z = {0.f, 0.f, 0.f, 0.f}; acc[mf][nf] = z; }

    f32x4 avc, avn;
    bf16x8 bC[4], bN[4];

    // prologue: tile0 -> buf0; tile1 -> regs; preload B(t=0)
    avc = ntload4(pA);
    {
        u32* d = reinterpret_cast<u32*>(As[0]);
        d[wslot] = cvtpk(avc[0], avc[1]);
        d[wslot + 1] = cvtpk(avc[2], avc[3]);
    }
    avc = ntload4(pA + 32);
#pragma unroll
    for (int nf = 0; nf < 4; ++nf)
        bC[nf] = *reinterpret_cast<const bf16x8*>(wq + ((size_t)((uq0 + nf) * 32 + 0) << 9));
    asm volatile("s_waitcnt lgkmcnt(0)" ::: "memory");
    __builtin_amdgcn_s_barrier();

#pragma unroll 1
    for (int t = 0; t < 32; ++t) {
        const int cur = t & 1;
        // A frags from LDS
        bf16x8 aF[4];
#pragma unroll
        for (int mf = 0; mf < 4; ++mf)
            aF[mf] = *reinterpret_cast<const bf16x8*>(&As[cur][(mf * 16 + arow) * AST + kgrp]);
        // prefetch next-step B (in flight across barrier) and next-next A tile
        if (t < 31) {
#pragma unroll
            for (int nf = 0; nf < 4; ++nf)
                bN[nf] = *reinterpret_cast<const bf16x8*>(
                    wq + ((size_t)((uq0 + nf) * 32 + t + 1) << 9));
            const int tn = (t + 2 < 32) ? (t + 2) : 31;
            avn = ntload4(pA + tn * 32);
        }
        // 16 MFMA on current B
#pragma unroll
        for (int mf = 0; mf < 4; ++mf)
#pragma unroll
            for (int nf = 0; nf < 4; ++nf)
                acc[mf][nf] = __builtin_amdgcn_mfma_f32_16x16x32_bf16(
                    aF[mf], bC[nf], acc[mf][nf], 0, 0, 0);
        // write tile t+1 into other buffer; rotate rings
        if (t < 31) {
            u32* d = reinterpret_cast<u32*>(As[cur ^ 1]);
            d[wslot] = cvtpk(avc[0], avc[1]);
            d[wslot + 1] = cvtpk(avc[2], avc[3]);
            avc = avn;
#pragma unroll
            for (int nf = 0; nf < 4; ++nf) bC[nf] = bN[nf];
        }
        asm volatile("s_waitcnt lgkmcnt(0)" ::: "memory");
        __builtin_amdgcn_s_barrier();
    }

    // epilogue: tanh + wv weighting (R2-verified 16x16 C/D layout: col=lane&15,
    // row=(lane>>4)*4+i)
    float rowsum[16];
#pragma unroll
    for (int i = 0; i < 16; ++i) rowsum[i] = 0.f;
#pragma unroll
    for (int nf = 0; nf < 4; ++nf) {
        const int u = (uq0 + nf) * 16 + arow;
        const float qv = qp2[b * UU + u];
        const float wvv = wv[u];
#pragma unroll
        for (int mf = 0; mf < 4; ++mf)
#pragma unroll
            for (int i = 0; i < 4; ++i) {
                float h = acc[mf][nf][i] + qv;
                float e = __expf(2.f * h);
                float th = 1.f - 2.f / (e + 1.f);
                rowsum[mf * 4 + i] = fmaf(th, wvv, rowsum[mf * 4 + i]);
            }
    }
    // reduce over the 16 cols held by each 16-lane group
#pragma unroll
    for (int i = 0; i < 16; ++i) {
        float v = rowsum[i];
        v += __shfl_xor(v, 1);
        v += __shfl_xor(v, 2);
        v += __shfl_xor(v, 4);
        v += __shfl_xor(v, 8);
        rowsum[i] = v;
    }
    if ((lane & 15) == 0) {
        const int rg = lane >> 4;
#pragma unroll
        for (int mf = 0; mf < 4; ++mf)
#pragma unroll
            for (int i = 0; i < 4; ++i)
                ssum[wid][mf * 16 + rg * 4 + i] = rowsum[mf * 4 + i];
    }
    __syncthreads();
    if (tid < MBLK) {
        float sc2 = 0.f;
#pragma unroll
        for (int w = 0; w < 8; ++w) sc2 += ssum[w][tid];
        atomicAdd(&score[b * SS + s0 + tid], sc2);
    }
}

// ---------------- K3a: softmax over S per batch ----------------
__global__ void softmax_kernel(const float* __restrict__ score, float* __restrict__ weights) {
    __shared__ float red[8];
    const int b = blockIdx.x;
    const int t = threadIdx.x;  // 256
    float local[8];
    float mx = -1e30f;
#pragma unroll
    for (int i = 0; i < 8; ++i) {
        local[i] = score[b * SS + i * 256 + t];
        mx = fmaxf(mx, local[i]);
    }
    for (int off = 1; off < 64; off <<= 1) mx = fmaxf(mx, __shfl_xor(mx, off));
    if ((t & 63) == 0) red[t >> 6] = mx;
    __syncthreads();
    const float m = fmaxf(fmaxf(red[0], red[1]), fmaxf(red[2], red[3]));
    float sum = 0.f;
#pragma unroll
    for (int i = 0; i < 8; ++i) {
        local[i] = __expf(local[i] - m);
        sum += local[i];
    }
    for (int off = 1; off < 64; off <<= 1) sum += __shfl_xor(sum, off);
    if ((t & 63) == 0) red[4 + (t >> 6)] = sum;
    __syncthreads();
    const float inv = 1.f / (red[4] + red[5] + red[6] + red[7]);
#pragma unroll
    for (int i = 0; i < 8; ++i) weights[b * SS + i * 256 + t] = local[i] * inv;
}

// ---------------- K3b: context[b,d] = sum_s w[b,s] * values[b,s,d] ----------------
__global__ void context_kernel(const float* __restrict__ values, const float* __restrict__ weights,
                               float* __restrict__ ctx) {
    __shared__ float ws[SS];          // 8 KB
    __shared__ f32x4 red[16][16];     // 4 KB
    const int b = blockIdx.x;   // 32
    const int dc = blockIdx.y;  // 16
    const int t = threadIdx.x;  // 256
    for (int i = t; i < SS; i += 256) ws[i] = weights[b * SS + i];
    __syncthreads();
    const int dt = t & 15;      // 16 d-threads (64 cols)
    const int ph = t >> 4;      // 16 s-phases
    const int d = dc * 64 + dt * 4;
    const float* vb = values + (size_t)b * SS * DD + d;
    f32x4 acc = {0.f, 0.f, 0.f, 0.f};
#pragma unroll 8
    for (int s = ph; s < SS; s += 16) {
        const float w = ws[s];
        f32x4 v = ntload4(vb + (size_t)s * DD);
        acc[0] = fmaf(w, v[0], acc[0]);
        acc[1] = fmaf(w, v[1], acc[1]);
        acc[2] = fmaf(w, v[2], acc[2]);
        acc[3] = fmaf(w, v[3], acc[3]);
    }
    red[ph][dt] = acc;
    __syncthreads();
    if (t < 16) {
        f32x4 r = red[0][t];
#pragma unroll
        for (int w = 1; w < 16; ++w) {
            f32x4 x = red[w][t];
#pragma unroll
            for (int i = 0; i < 4; ++i) r[i] += x[i];
        }
        *reinterpret_cast<f32x4*>(ctx + (size_t)b * DD + dc * 64 + t * 4) = r;
    }
}

extern "C" void kernel_launch(void* const* d_in, const int* in_sizes, int n_in,
                              void* d_out, int out_size, void* d_ws, size_t ws_size,
                              hipStream_t stream) {
    const float* query  = (const float*)d_in[0];
    const float* values = (const float*)d_in[1];
    const float* w1     = (const float*)d_in[2];
    const float* b1     = (const float*)d_in[3];
    const float* w2     = (const float*)d_in[4];
    const float* b2     = (const float*)d_in[5];
    const float* wv     = (const float*)d_in[6];

    float* ctx     = (float*)d_out;                    // [B, D]
    float* weights = (float*)d_out + (size_t)BB * DD;  // [B, S, 1]

    float* qp2           = (float*)d_ws;                                  // 128 KB
    unsigned short* w2q  = (unsigned short*)((char*)d_ws + 131072);       // 2 MB
    float* score         = (float*)((char*)d_ws + 131072 + 2097152);      // 256 KB

    zero_kernel<<<dim3(BB * SS / 256), 256, 0, stream>>>(score);
    qproj_kernel<<<dim3(BB, UU / 256), 256, 0, stream>>>(query, w1, b1, b2, qp2);
    w2q_kernel<<<dim3(512), 256, 0, stream>>>(w2, w2q);
    score_kernel<<<dim3(BB * SS / MBLK * 2), 512, 0, stream>>>(values, w2q, qp2, wv, score);
    softmax_kernel<<<dim3(BB), 256, 0, stream>>>(score, weights);
    context_kernel<<<dim3(BB, 16), 256, 0, stream>>>(values, weights, ctx);
}